// Round 1
// baseline (295.913 us; speedup 1.0000x reference)
//
#include <hip/hip_runtime.h>
#include <math.h>

#define NSCALE 0.44668359215096315f

__device__ __forceinline__ float eluf(float v)  { return v > 0.0f ? v : expm1f(v); }
__device__ __forceinline__ float reluf(float v) { return fmaxf(v, 0.0f); }

// recompute encoder: x[16] -> z[16]
__device__ __forceinline__ void encoder(const float xv[16],
                                        const float* __restrict__ ew1, const float* __restrict__ eb1,
                                        const float* __restrict__ ew2, const float* __restrict__ eb2,
                                        float z[16])
{
    float h1[16];
#pragma unroll
    for (int o = 0; o < 16; ++o) {
        float a = eb1[o];
#pragma unroll
        for (int k = 0; k < 16; ++k) a = fmaf(xv[k], ew1[o*16+k], a);
        h1[o] = eluf(a);
    }
#pragma unroll
    for (int o = 0; o < 16; ++o) {
        float a = eb2[o];
#pragma unroll
        for (int k = 0; k < 16; ++k) a = fmaf(h1[k], ew2[o*16+k], a);
        z[o] = a;
    }
}

// ---------------- Kernel A: z + per-block partial sums (deterministic) ----------------
__global__ __launch_bounds__(256) void kA(const float* __restrict__ x,
                                          const float* __restrict__ ew1, const float* __restrict__ eb1,
                                          const float* __restrict__ ew2, const float* __restrict__ eb2,
                                          float* __restrict__ partials, int B)
{
    int i = blockIdx.x * 256 + threadIdx.x;
    bool valid = i < B;
    float xv[16];
    if (valid) {
        const float4* xp = reinterpret_cast<const float4*>(x + (size_t)i * 16);
#pragma unroll
        for (int q = 0; q < 4; ++q) {
            float4 v = xp[q];
            xv[4*q+0] = v.x; xv[4*q+1] = v.y; xv[4*q+2] = v.z; xv[4*q+3] = v.w;
        }
    } else {
#pragma unroll
        for (int q = 0; q < 16; ++q) xv[q] = 0.0f;
    }
    float z[16];
    encoder(xv, ew1, eb1, ew2, eb2, z);
#pragma unroll
    for (int c = 0; c < 16; ++c) if (!valid) z[c] = 0.0f;

    __shared__ float wsum[4][32];
    int lane = threadIdx.x & 63, wave = threadIdx.x >> 6;
#pragma unroll
    for (int c = 0; c < 16; ++c) {
        float s = z[c];
        float q = z[c] * z[c];
#pragma unroll
        for (int m = 1; m < 64; m <<= 1) { s += __shfl_xor(s, m); q += __shfl_xor(q, m); }
        if (lane == 0) { wsum[wave][c] = s; wsum[wave][16 + c] = q; }
    }
    __syncthreads();
    if (threadIdx.x < 32) {
        float t = wsum[0][threadIdx.x] + wsum[1][threadIdx.x]
                + wsum[2][threadIdx.x] + wsum[3][threadIdx.x];
        partials[(size_t)blockIdx.x * 32 + threadIdx.x] = t;
    }
}

// ---------------- Kernel B: reduce partials -> BN affine (deterministic order) ----------------
__global__ __launch_bounds__(256) void kB(const float* __restrict__ partials, int nblk, int B,
                                          const float* __restrict__ bng, const float* __restrict__ bnb,
                                          float* __restrict__ bnp)
{
    int tid = threadIdx.x;
    int q = tid >> 3, k = tid & 7;
    int chunk = (nblk + 7) / 8;
    int j0 = k * chunk;
    int j1 = j0 + chunk; if (j1 > nblk) j1 = nblk;
    double s = 0.0;
    for (int j = j0; j < j1; ++j) s += (double)partials[(size_t)j * 32 + q];
    s += __shfl_xor(s, 4);
    s += __shfl_xor(s, 2);
    s += __shfl_xor(s, 1);
    __shared__ double tot[32];
    if (k == 0) tot[q] = s;
    __syncthreads();
    if (tid < 16) {
        double mu  = tot[tid] / (double)B;
        double var = tot[16 + tid] / (double)B - mu * mu;
        double a = (double)bng[tid] / sqrt(var + 1e-5);
        double b = (double)bnb[tid] - mu * a;
        bnp[tid]      = (float)a;
        bnp[16 + tid] = (float)b;
    }
}

// ---------------- Kernel C: full per-element pipeline ----------------
__global__ __launch_bounds__(256) void kC(
    const float* __restrict__ x, const float* __restrict__ noise, const float* __restrict__ fading,
    const float* __restrict__ ew1, const float* __restrict__ eb1,
    const float* __restrict__ ew2, const float* __restrict__ eb2,
    const float* __restrict__ bnp,
    const float* __restrict__ pc1w, const float* __restrict__ pc1b,
    const float* __restrict__ pc2w, const float* __restrict__ pc2b,
    const float* __restrict__ pc3w, const float* __restrict__ pc3b,
    const float* __restrict__ pc4w, const float* __restrict__ pc4b,
    const float* __restrict__ pc5w, const float* __restrict__ pc5b,
    const float* __restrict__ plw,  const float* __restrict__ plb,
    const float* __restrict__ dc1w, const float* __restrict__ dc1b,
    const float* __restrict__ dc2w, const float* __restrict__ dc2b,
    const float* __restrict__ dc3w, const float* __restrict__ dc3b,
    const float* __restrict__ dc4w, const float* __restrict__ dc4b,
    const float* __restrict__ dl1w, const float* __restrict__ dl1b,
    const float* __restrict__ dl2w, const float* __restrict__ dl2b,
    const float* __restrict__ dl3w, const float* __restrict__ dl3b,
    float* __restrict__ out, int B)
{
    int i = blockIdx.x * 256 + threadIdx.x;
    if (i >= B) return;

    // ---- encoder recompute + BN affine ----
    float xv[16];
    {
        const float4* xp = reinterpret_cast<const float4*>(x + (size_t)i * 16);
#pragma unroll
        for (int q = 0; q < 4; ++q) {
            float4 v = xp[q];
            xv[4*q+0] = v.x; xv[4*q+1] = v.y; xv[4*q+2] = v.z; xv[4*q+3] = v.w;
        }
    }
    float z[16];
    encoder(xv, ew1, eb1, ew2, eb2, z);
    float zn[16];
#pragma unroll
    for (int c = 0; c < 16; ++c) zn[c] = fmaf(z[c], bnp[c], bnp[16 + c]);

    // ---- channel: 3-tap causal complex FIR + AWGN ----
    float f[6];
    {
        const float2* fp = reinterpret_cast<const float2*>(fading + (size_t)i * 6);
#pragma unroll
        for (int q = 0; q < 3; ++q) { float2 v = fp[q]; f[2*q] = v.x; f[2*q+1] = v.y; }
    }
    float cr[16];
#pragma unroll
    for (int n = 0; n < 8; ++n) {
        float re = f[0]*zn[2*n]   - f[1]*zn[2*n+1];
        float im = f[0]*zn[2*n+1] + f[1]*zn[2*n];
        if (n >= 1) { re += f[2]*zn[2*n-2] - f[3]*zn[2*n-1];
                      im += f[2]*zn[2*n-1] + f[3]*zn[2*n-2]; }
        if (n >= 2) { re += f[4]*zn[2*n-4] - f[5]*zn[2*n-3];
                      im += f[4]*zn[2*n-3] + f[5]*zn[2*n-4]; }
        cr[2*n] = re; cr[2*n+1] = im;
    }
    {
        const float4* np_ = reinterpret_cast<const float4*>(noise + (size_t)i * 16);
#pragma unroll
        for (int q = 0; q < 4; ++q) {
            float4 v = np_[q];
            cr[4*q+0] = fmaf(v.x, NSCALE, cr[4*q+0]);
            cr[4*q+1] = fmaf(v.y, NSCALE, cr[4*q+1]);
            cr[4*q+2] = fmaf(v.z, NSCALE, cr[4*q+2]);
            cr[4*q+3] = fmaf(v.w, NSCALE, cr[4*q+3]);
        }
    }

    // ---- p-convs (only the 9 pc1 / 6 pc2 columns pc3's stride-4 needs) ----
    float p4[3][16];
#pragma unroll
    for (int g = 0; g < 3; ++g) {
        const int base = 4 * g;
        float p1c[3][16];
#pragma unroll
        for (int c2 = 0; c2 < 3; ++c2) {
            const int t = base + c2;
#pragma unroll
            for (int o = 0; o < 16; ++o) {
                float a = pc1b[o];
#pragma unroll
                for (int k = 0; k < 4; ++k) a = fmaf(pc1w[o*4+k], cr[t+k], a);
                p1c[c2][o] = reluf(a);
            }
        }
        float p2c[2][16];
#pragma unroll
        for (int c2 = 0; c2 < 2; ++c2) {
#pragma unroll
            for (int o = 0; o < 16; ++o) {
                float a = pc2b[o];
#pragma unroll
                for (int ci = 0; ci < 16; ++ci) {
                    a = fmaf(pc2w[o*32+ci*2+0], p1c[c2+0][ci], a);
                    a = fmaf(pc2w[o*32+ci*2+1], p1c[c2+1][ci], a);
                }
                p2c[c2][o] = reluf(a);
            }
        }
        float p3c[16];
#pragma unroll
        for (int o = 0; o < 16; ++o) {
            float a = pc3b[o];
#pragma unroll
            for (int ci = 0; ci < 16; ++ci) {
                a = fmaf(pc3w[o*32+ci*2+0], p2c[0][ci], a);
                a = fmaf(pc3w[o*32+ci*2+1], p2c[1][ci], a);
            }
            p3c[o] = reluf(a);
        }
#pragma unroll
        for (int o = 0; o < 16; ++o) {
            float a = pc4b[o];
#pragma unroll
            for (int ci = 0; ci < 16; ++ci) a = fmaf(pc4w[o*16+ci], p3c[ci], a);
            p4[g][o] = reluf(a);
        }
    }
    float hh[16];
    {
        float p5[16];
#pragma unroll
        for (int o = 0; o < 16; ++o) {
            float a = pc5b[o];
#pragma unroll
            for (int ci = 0; ci < 16; ++ci) {
                a = fmaf(pc5w[o*48+ci*3+0], p4[0][ci], a);
                a = fmaf(pc5w[o*48+ci*3+1], p4[1][ci], a);
                a = fmaf(pc5w[o*48+ci*3+2], p4[2][ci], a);
            }
            p5[o] = reluf(a);
        }
#pragma unroll
        for (int o = 0; o < 16; ++o) {
            float a = plb[o];
#pragma unroll
            for (int ci = 0; ci < 16; ++ci) a = fmaf(plw[o*16+ci], p5[ci], a);
            hh[o] = a;
        }
    }

    // ---- complex equalizer t = cc / hh ----
    float tr[16];
#pragma unroll
    for (int n = 0; n < 8; ++n) {
        float a = cr[2*n], b = cr[2*n+1];
        float c = hh[2*n], d = hh[2*n+1];
        float inv = 1.0f / (c*c + d*d);
        tr[2*n]   = (a*c + b*d) * inv;
        tr[2*n+1] = (b*c - a*d) * inv;
    }

    // ---- d-convs, streamed column-wise into dl1 accumulation ----
    float y[16];
#pragma unroll
    for (int o = 0; o < 16; ++o) y[o] = dl1b[o];
#pragma unroll
    for (int t = 0; t < 8; ++t) {
        float d1a[8], d1b[8];
#pragma unroll
        for (int c = 0; c < 8; ++c) {
            d1a[c] = reluf(fmaf(dc1w[c], tr[2*t+0], dc1b[c]));
            d1b[c] = reluf(fmaf(dc1w[c], tr[2*t+1], dc1b[c]));
        }
        float d2[8];
#pragma unroll
        for (int c = 0; c < 8; ++c) {
            float a = dc2b[c];
#pragma unroll
            for (int ci = 0; ci < 8; ++ci) {
                a = fmaf(dc2w[c*16+ci*2+0], d1a[ci], a);
                a = fmaf(dc2w[c*16+ci*2+1], d1b[ci], a);
            }
            d2[c] = reluf(a);
        }
        float d3[8];
#pragma unroll
        for (int c = 0; c < 8; ++c) {
            float a = dc3b[c];
#pragma unroll
            for (int ci = 0; ci < 8; ++ci) a = fmaf(dc3w[c*8+ci], d2[ci], a);
            d3[c] = reluf(a);
        }
        float d4[8];
#pragma unroll
        for (int c = 0; c < 8; ++c) {
            float a = dc4b[c];
#pragma unroll
            for (int ci = 0; ci < 8; ++ci) a = fmaf(dc4w[c*8+ci], d3[ci], a);
            d4[c] = reluf(a);
        }
#pragma unroll
        for (int o = 0; o < 16; ++o) {
            float a = y[o];
#pragma unroll
            for (int c = 0; c < 8; ++c) a = fmaf(dl1w[o*64 + c*8 + t], d4[c], a);
            y[o] = a;
        }
    }
#pragma unroll
    for (int o = 0; o < 16; ++o) y[o] = reluf(y[o]);
    float h2[16];
#pragma unroll
    for (int o = 0; o < 16; ++o) {
        float a = dl2b[o];
#pragma unroll
        for (int ci = 0; ci < 16; ++ci) a = fmaf(dl2w[o*16+ci], y[ci], a);
        h2[o] = eluf(a);
    }
    float o16[16];
#pragma unroll
    for (int o = 0; o < 16; ++o) {
        float a = dl3b[o];
#pragma unroll
        for (int ci = 0; ci < 16; ++ci) a = fmaf(dl3w[o*16+ci], h2[ci], a);
        o16[o] = a;
    }
    float4* op = reinterpret_cast<float4*>(out + (size_t)i * 16);
    op[0] = make_float4(o16[0],  o16[1],  o16[2],  o16[3]);
    op[1] = make_float4(o16[4],  o16[5],  o16[6],  o16[7]);
    op[2] = make_float4(o16[8],  o16[9],  o16[10], o16[11]);
    op[3] = make_float4(o16[12], o16[13], o16[14], o16[15]);
}

extern "C" void kernel_launch(void* const* d_in, const int* in_sizes, int n_in,
                              void* d_out, int out_size, void* d_ws, size_t ws_size,
                              hipStream_t stream)
{
    const float* x      = (const float*)d_in[0];
    const float* noise  = (const float*)d_in[1];
    const float* fading = (const float*)d_in[2];
    const float* ew1  = (const float*)d_in[3];
    const float* eb1  = (const float*)d_in[4];
    const float* ew2  = (const float*)d_in[5];
    const float* eb2  = (const float*)d_in[6];
    const float* bng  = (const float*)d_in[7];
    const float* bnb  = (const float*)d_in[8];
    const float* pc1w = (const float*)d_in[9];
    const float* pc1b = (const float*)d_in[10];
    const float* pc2w = (const float*)d_in[11];
    const float* pc2b = (const float*)d_in[12];
    const float* pc3w = (const float*)d_in[13];
    const float* pc3b = (const float*)d_in[14];
    const float* pc4w = (const float*)d_in[15];
    const float* pc4b = (const float*)d_in[16];
    const float* pc5w = (const float*)d_in[17];
    const float* pc5b = (const float*)d_in[18];
    const float* plw  = (const float*)d_in[19];
    const float* plb  = (const float*)d_in[20];
    const float* dc1w = (const float*)d_in[21];
    const float* dc1b = (const float*)d_in[22];
    const float* dc2w = (const float*)d_in[23];
    const float* dc2b = (const float*)d_in[24];
    const float* dc3w = (const float*)d_in[25];
    const float* dc3b = (const float*)d_in[26];
    const float* dc4w = (const float*)d_in[27];
    const float* dc4b = (const float*)d_in[28];
    const float* dl1w = (const float*)d_in[29];
    const float* dl1b = (const float*)d_in[30];
    const float* dl2w = (const float*)d_in[31];
    const float* dl2b = (const float*)d_in[32];
    const float* dl3w = (const float*)d_in[33];
    const float* dl3b = (const float*)d_in[34];

    int B = in_sizes[0] / 16;
    int nblk = (B + 255) / 256;

    float* partials = (float*)d_ws;                 // nblk*32 floats
    float* bnp = partials + (size_t)nblk * 32;      // 32 floats (scale, shift)

    kA<<<nblk, 256, 0, stream>>>(x, ew1, eb1, ew2, eb2, partials, B);
    kB<<<1, 256, 0, stream>>>(partials, nblk, B, bng, bnb, bnp);
    kC<<<nblk, 256, 0, stream>>>(x, noise, fading,
                                 ew1, eb1, ew2, eb2, bnp,
                                 pc1w, pc1b, pc2w, pc2b, pc3w, pc3b, pc4w, pc4b, pc5w, pc5b,
                                 plw, plb,
                                 dc1w, dc1b, dc2w, dc2b, dc3w, dc3b, dc4w, dc4b,
                                 dl1w, dl1b, dl2w, dl2b, dl3w, dl3b,
                                 (float*)d_out, B);
}